// Round 4
// baseline (160.389 us; speedup 1.0000x reference)
//
#include <hip/hip_runtime.h>
#include <hip/hip_bf16.h>

// out[bn,e] = relu(relu(hp[bn]+ep[e]+b1) @ W2 + b2) @ W3 + b3
// R8: 128-row blocks (halves L2 B-stream per matrix-cycle: 0.92x -> 0.46x),
// full-K x1 resident in 128KB LDS (staged once, no re-staging), 512 thr =
// 8 waves (2 row-groups x 4 col-groups); per-wave inner loop is R4's verbatim
// (j-fan 8, acc[4][8], bunched A-reads at top, bunched B-reloads after MFMAs,
// depth-2 B ping-pong). LDS records lane-linear (R6's zero-conflict pattern).
// Stagger dropped: 1 block/CU, rg-partner waves share B records -> L1 hits.

typedef __attribute__((ext_vector_type(8))) short bf16x8;   // 8 bf16
typedef __attribute__((ext_vector_type(4))) float f32x4;    // 16x16 MFMA acc

static __device__ __forceinline__ ushort2 pk_bf16(float a, float b) {
  union { __hip_bfloat162 h; ushort2 u; } c;
  c.h = __float22bfloat162_rn(make_float2(a, b));
  return c.u;
}
static __device__ __forceinline__ float bf2f(unsigned short u) {
  union { unsigned int i; float f; } c;
  c.i = ((unsigned int)u) << 16;
  return c.f;
}

// ---------------- fused prep (352 blocks x 256 thr) ----------------
// blocks 0..255  : hpb rows (2/blk)  hpb[r][k] = bf16(sum_h h[r][h]*W1[h][k] + b1[k])
// blocks 256..287: epb rows (8/blk)  epb[e][k] = bf16(sum_d e[e][d]*W1[256+d][k])
// blocks 288..351: w2f pack (64x64 W2 tile -> bf16 B-frag records, 16x16x32)
//   record(jg,ks): lane l holds W2[k = ks*32+(l>>4)*8 + u][col = jg*16+(l&15)], u=0..7
__global__ __launch_bounds__(256) void k_prep(
    const float* __restrict__ h_all, const float* __restrict__ e_feat,
    const float* __restrict__ W1, const float* __restrict__ b1,
    const float* __restrict__ W2,
    unsigned short* __restrict__ hpb, unsigned short* __restrict__ epb,
    unsigned short* __restrict__ w2f) {
  __shared__ float sm[64 * 68];   // 17408 B, reused per role
  const int t = threadIdx.x;
  const int b = blockIdx.x;

  if (b < 256) {                      // ---- hp part: 2 rows, bf16 out
    const int r0 = b * 2;
    float (*hs)[256] = (float(*)[256])sm;
    hs[0][t] = h_all[(size_t)r0 * 256 + t];
    hs[1][t] = h_all[(size_t)(r0 + 1) * 256 + t];
    __syncthreads();
    float2 a0 = make_float2(0.f, 0.f), a1 = make_float2(0.f, 0.f);
    #pragma unroll 2
    for (int k = 0; k < 256; k += 4) {
      float2 w0 = *(const float2*)(W1 + (size_t)k * 512 + 2 * t);
      float2 w1 = *(const float2*)(W1 + (size_t)(k + 1) * 512 + 2 * t);
      float2 w2v = *(const float2*)(W1 + (size_t)(k + 2) * 512 + 2 * t);
      float2 w3v = *(const float2*)(W1 + (size_t)(k + 3) * 512 + 2 * t);
      float h00 = hs[0][k], h01 = hs[0][k + 1], h02 = hs[0][k + 2], h03 = hs[0][k + 3];
      float h10 = hs[1][k], h11 = hs[1][k + 1], h12 = hs[1][k + 2], h13 = hs[1][k + 3];
      a0.x = fmaf(h00, w0.x, a0.x); a0.y = fmaf(h00, w0.y, a0.y);
      a1.x = fmaf(h10, w0.x, a1.x); a1.y = fmaf(h10, w0.y, a1.y);
      a0.x = fmaf(h01, w1.x, a0.x); a0.y = fmaf(h01, w1.y, a0.y);
      a1.x = fmaf(h11, w1.x, a1.x); a1.y = fmaf(h11, w1.y, a1.y);
      a0.x = fmaf(h02, w2v.x, a0.x); a0.y = fmaf(h02, w2v.y, a0.y);
      a1.x = fmaf(h12, w2v.x, a1.x); a1.y = fmaf(h12, w2v.y, a1.y);
      a0.x = fmaf(h03, w3v.x, a0.x); a0.y = fmaf(h03, w3v.y, a0.y);
      a1.x = fmaf(h13, w3v.x, a1.x); a1.y = fmaf(h13, w3v.y, a1.y);
    }
    float2 bv = *(const float2*)(b1 + 2 * t);
    *(ushort2*)(hpb + (size_t)r0 * 512 + 2 * t) = pk_bf16(a0.x + bv.x, a0.y + bv.y);
    *(ushort2*)(hpb + (size_t)(r0 + 1) * 512 + 2 * t) = pk_bf16(a1.x + bv.x, a1.y + bv.y);
  } else if (b < 288) {               // ---- ep part: 8 rows, bf16 out
    const int r0 = (b - 256) * 8;
    sm[t] = e_feat[(size_t)r0 * 64 + t];
    sm[256 + t] = e_feat[(size_t)r0 * 64 + 256 + t];
    __syncthreads();
    float2 acc[8];
    #pragma unroll
    for (int i = 0; i < 8; ++i) acc[i] = make_float2(0.f, 0.f);
    for (int k = 0; k < 64; ++k) {
      float2 wv = *(const float2*)(W1 + (size_t)(256 + k) * 512 + 2 * t);
      #pragma unroll
      for (int i = 0; i < 8; ++i) {
        acc[i].x = fmaf(sm[i * 64 + k], wv.x, acc[i].x);
        acc[i].y = fmaf(sm[i * 64 + k], wv.y, acc[i].y);
      }
    }
    #pragma unroll
    for (int i = 0; i < 8; ++i)
      *(ushort2*)(epb + (size_t)(r0 + i) * 512 + 2 * t) = pk_bf16(acc[i].x, acc[i].y);
  } else {                            // ---- w2f pack
    const int bb = b - 288;           // 0..63
    const int k0 = (bb >> 3) * 64;
    const int c0 = (bb & 7) * 64;
    #pragma unroll
    for (int rr = 0; rr < 4; ++rr) {
      const int row = rr * 16 + (t >> 4);
      float4 v = *(const float4*)(W2 + (size_t)(k0 + row) * 512 + c0 + (t & 15) * 4);
      *(float4*)(&sm[row * 68 + (t & 15) * 4]) = v;
    }
    __syncthreads();
    #pragma unroll
    for (int s2 = 0; s2 < 2; ++s2) {
      const int s = t * 2 + s2;       // 0..511 (8 records x 64 lanes)
      const int rec = s >> 6, l = s & 63;
      const int jg = (c0 >> 4) + (rec & 3);
      const int ksg = (k0 >> 5) + (rec >> 2);
      const int cl = (rec & 3) * 16 + (l & 15);
      const int kl = (rec >> 2) * 32 + (l >> 4) * 8;
      union { ushort2 o[4]; uint4 v; } u;
      #pragma unroll
      for (int uu = 0; uu < 4; ++uu)
        u.o[uu] = pk_bf16(sm[(kl + 2 * uu) * 68 + cl], sm[(kl + 2 * uu + 1) * 68 + cl]);
      *(uint4*)(w2f + ((size_t)(jg * 16 + ksg) * 64 + l) * 8) = u.v;
    }
  }
}

// ---------------- main fused kernel ----------------
// 1024 blocks x 512 thr (8 waves, 1 blk/CU). Block = 128 rows (one bn,
// e-half) x all 512 cols. Wave w: rg = w>>2 (rows rg*64..+64),
// cg = w&3 (cols cg*128..+128, j=0..7). acc[4][8] f32x4 (R4 shape).
// x1 LDS: full K resident, 128 records (rt 0..7, ks 0..15) of 1KB:
// slot l of rec(rt,ks) = x1[rt*16+(l&15)][ks*32+(l>>4)*8+u] -> all ds ops
// are base+lane*16 (R6's measured-zero-conflict pattern).
__global__ __launch_bounds__(512, 2) void k_main(
    const unsigned short* __restrict__ hpb, const unsigned short* __restrict__ epb,
    const unsigned short* __restrict__ w2f, const float* __restrict__ b2,
    const float* __restrict__ W3, const float* __restrict__ b3,
    float* __restrict__ out) {
  __shared__ unsigned short x1s[128 * 512];   // 128 KiB

  const int t = threadIdx.x;
  const int lane = t & 63;
  const int w = t >> 6;            // 0..7
  const int l15 = lane & 15, l4 = lane >> 4;
  const int rg = w >> 2;           // row group: rows rg*64 .. +64
  const int cg = w & 3;            // col group: cols cg*128 .. +128
  const int bn = blockIdx.x >> 1;
  const int e0 = (blockIdx.x & 1) << 7;      // e-half (128 rows)
  const unsigned short* hprow = hpb + (size_t)bn * 512;

  // B-frag ping-pong: wave's col group cg -> jg = cg*8 .. +8
  const unsigned short* wrec = w2f + (size_t)cg * 65536 + (size_t)lane * 8;
  bf16x8 bb[2][8];
  #pragma unroll
  for (int j = 0; j < 8; ++j) {
    bb[0][j] = *(const bf16x8*)(wrec + j * 8192);
    bb[1][j] = *(const bf16x8*)(wrec + j * 8192 + 512);
  }

  // ---- stage x1 once, record order: wave w owns row-tile rt = w (16 rows)
  // lane l: row = w*16 + l15 (fixed), k = ks*32 + l4*8 .. +8
  {
    const unsigned short* eprow = epb + (size_t)(e0 + w * 16 + l15) * 512;
    #pragma unroll 4
    for (int ks = 0; ks < 16; ++ks) {
      const int k0 = ks * 32 + l4 * 8;
      union { uint4 v; unsigned short s[8]; } hv, ev, ov;
      hv.v = *(const uint4*)(hprow + k0);
      ev.v = *(const uint4*)(eprow + k0);
      #pragma unroll
      for (int u = 0; u < 4; ++u) {
        ushort2 p = pk_bf16(fmaxf(bf2f(hv.s[2 * u]) + bf2f(ev.s[2 * u]), 0.f),
                            fmaxf(bf2f(hv.s[2 * u + 1]) + bf2f(ev.s[2 * u + 1]), 0.f));
        ov.s[2 * u] = p.x;
        ov.s[2 * u + 1] = p.y;
      }
      *(uint4*)(&x1s[(size_t)(w * 16 + ks) * 512 + lane * 8]) = ov.v;
    }
  }
  __syncthreads();

  // ---- K loop: 16 steps of K=32; R4's verbatim inner structure
  f32x4 acc[4][8] = {};
  #pragma unroll 4
  for (int ks = 0; ks < 16; ++ks) {
    const int cur = ks & 1;
    const int krb = (ks + 2) & 15;        // B prefetch slot (wraps: dummy reload)
    bf16x8 a[4];
    #pragma unroll
    for (int i = 0; i < 4; ++i)
      a[i] = *(const bf16x8*)(&x1s[(size_t)(((rg * 4 + i) * 16) + ks) * 512 + lane * 8]);
    #pragma unroll
    for (int i = 0; i < 4; ++i)
      #pragma unroll
      for (int j = 0; j < 8; ++j)
        acc[i][j] = __builtin_amdgcn_mfma_f32_16x16x32_bf16(a[i], bb[cur][j], acc[i][j], 0, 0, 0);
    #pragma unroll
    for (int j = 0; j < 8; ++j)
      bb[cur][j] = *(const bf16x8*)(wrec + j * 8192 + (size_t)krb * 512);
  }

  // ---- fused epilogue: osum[row] = sum_n relu(acc + b2[n]) * W3[n]
  float part[16];
  #pragma unroll
  for (int u = 0; u < 16; ++u) part[u] = 0.f;
  #pragma unroll
  for (int j = 0; j < 8; ++j) {
    const int n = cg * 128 + j * 16 + l15;
    const float b2v = b2[n], w3v = W3[n];
    #pragma unroll
    for (int i = 0; i < 4; ++i)
      #pragma unroll
      for (int r = 0; r < 4; ++r)
        part[i * 4 + r] = fmaf(fmaxf(acc[i][j][r] + b2v, 0.f), w3v, part[i * 4 + r]);
  }
  #pragma unroll
  for (int u = 0; u < 16; ++u) {     // reduce over the 16 col-lanes (l15)
    float v = part[u];
    v += __shfl_xor(v, 1);
    v += __shfl_xor(v, 2);
    v += __shfl_xor(v, 4);
    v += __shfl_xor(v, 8);
    part[u] = v;
  }
  __syncthreads();                   // all x1s reads done before aliasing
  float* osum = (float*)x1s;         // [4 col-groups][128 rows] = 2 KiB
  if (l15 == 0) {
    #pragma unroll
    for (int i = 0; i < 4; ++i)
      #pragma unroll
      for (int r = 0; r < 4; ++r)
        osum[cg * 128 + rg * 64 + i * 16 + l4 * 4 + r] = part[i * 4 + r];
  }
  __syncthreads();
  if (t < 128) {
    float s = b3[0] + osum[t] + osum[128 + t] + osum[256 + t] + osum[384 + t];
    out[(size_t)bn * 256 + e0 + t] = s;
  }
}

extern "C" void kernel_launch(void* const* d_in, const int* in_sizes, int n_in,
                              void* d_out, int out_size, void* d_ws, size_t ws_size,
                              hipStream_t stream) {
  const float* h_all  = (const float*)d_in[0];   // (8,64,256)
  const float* e_feat = (const float*)d_in[1];   // (256,64)
  const float* W1     = (const float*)d_in[2];   // (320,512)
  const float* b1     = (const float*)d_in[3];   // (512,)
  const float* W2     = (const float*)d_in[4];   // (512,512)
  const float* b2     = (const float*)d_in[5];   // (512,)
  const float* W3     = (const float*)d_in[6];   // (512,1)
  const float* b3     = (const float*)d_in[7];   // (1,)
  float* out = (float*)d_out;                    // 131072 f32

  // workspace: hpb 512KB bf16 | epb 256KB bf16 | w2f 512KB bf16
  unsigned short* hpb = (unsigned short*)d_ws;
  unsigned short* epb = hpb + 512 * 512;
  unsigned short* w2f = epb + 256 * 512;

  hipLaunchKernelGGL(k_prep, dim3(352), dim3(256), 0, stream,
                     h_all, e_feat, W1, b1, W2, hpb, epb, w2f);
  hipLaunchKernelGGL(k_main, dim3(1024), dim3(512), 0, stream,
                     hpb, epb, w2f, b2, W3, b3, out);
}